// Round 5
// baseline (299.748 us; speedup 1.0000x reference)
//
#include <hip/hip_runtime.h>
#include <hip/hip_bf16.h>

// Problem constants
#define NDIM 256   // outer n
#define QDIM 256   // q/k sequence
#define CDIM 128   // channels
#define HH 4       // heads
#define DD 32      // head dim
#define RROWS (NDIM * QDIM)  // 65536 flattened rows

// ---------- bf16 helpers (raw ushort storage, fp32 compute) ----------
__device__ __forceinline__ float bf2f(unsigned short u) {
    unsigned int x = ((unsigned int)u) << 16;
    return __uint_as_float(x);
}
__device__ __forceinline__ unsigned short f2bf(float f) {
    unsigned int x = __float_as_uint(f);
    unsigned int lsb = (x >> 16) & 1u;
    x += 0x7fffu + lsb;   // round-to-nearest-even
    return (unsigned short)(x >> 16);
}

// MFMA fragment types (gfx950: mfma_f32_16x16x32_bf16)
typedef __bf16 bf16x8v __attribute__((ext_vector_type(8)));
typedef float  f32x4v  __attribute__((ext_vector_type(4)));
union frag_u { uint4 u; bf16x8v v; };

__device__ __forceinline__ bf16x8v cvt8(float4 f0, float4 f1) {
    bf16x8v r;
    r[0] = (__bf16)f0.x; r[1] = (__bf16)f0.y; r[2] = (__bf16)f0.z; r[3] = (__bf16)f0.w;
    r[4] = (__bf16)f1.x; r[5] = (__bf16)f1.y; r[6] = (__bf16)f1.z; r[7] = (__bf16)f1.w;
    return r;
}

// =====================================================================
// Kernel 0: weight prep. 40 blocks (5 matrices x 8 k-chunks of 16).
// wt[p][n][k] = bf16(W_p[k][n])   (transposed so B-frags are contiguous)
// =====================================================================
__global__ __launch_bounds__(256, 1) void prep_weights(
    const float* __restrict__ Wq, const float* __restrict__ Wk,
    const float* __restrict__ Wv, const float* __restrict__ Wg,
    const float* __restrict__ Wo, unsigned short* __restrict__ wt)
{
    __shared__ unsigned short t[16][130];   // pad 130: conflict-free column reads
    const int p  = blockIdx.x >> 3;
    const int ch = blockIdx.x & 7;          // 16-row k-chunk
    const float* __restrict__ W = (p == 0) ? Wq : (p == 1) ? Wk :
                                  (p == 2) ? Wv : (p == 3) ? Wg : Wo;
    const int tid = threadIdx.x;
    for (int idx = tid; idx < 2048; idx += 256) {
        int k = idx >> 7, n = idx & 127;
        t[k][n] = f2bf(W[(ch * 16 + k) * 128 + n]);
    }
    __syncthreads();
    unsigned short* dst = wt + (size_t)p * 16384;
    for (int idx = tid; idx < 2048; idx += 256) {
        int n = idx >> 4, k = idx & 15;
        dst[n * 128 + ch * 16 + k] = t[k][n];   // Wt[n][k] = W[k][n]
    }
}

// =====================================================================
// Kernel 1: fused MFMA projections. grid (RROWS/128, 2), 512 thr.
//   pp=0: X=qx  -> q (scaled, [n][h][q][32]) and g (sigmoid, [n][h][q][32])
//   pp=1: X=kvx -> k ([n][h][k][32]) and v TRANSPOSED ([n][h][d][key])
// Weights LDS-resident (64 KB, XOR-swizzled).  (unchanged from round 4)
// =====================================================================
__global__ __launch_bounds__(512, 4) void proj_mfma(
    const float* __restrict__ qx, const float* __restrict__ kvx,
    const unsigned short* __restrict__ wt,
    unsigned short* __restrict__ q_ws, unsigned short* __restrict__ k_ws,
    unsigned short* __restrict__ v_ws, unsigned short* __restrict__ g_ws)
{
    __shared__ unsigned short wl[2 * 16384];   // 64 KB: WtA | WtB, swizzled
    const int tid = threadIdx.x;               // 0..511
    const int pp = blockIdx.y;
    const float* __restrict__ X = pp ? kvx : qx;
    const unsigned short* __restrict__ WtA = wt + (size_t)(pp ? 1 : 0) * 16384;
    const unsigned short* __restrict__ WtB = wt + (size_t)(pp ? 2 : 3) * 16384;

    const int wv   = tid >> 6;     // 0..7
    const int lane = tid & 63;
    const int col  = lane & 15;
    const int quad = lane >> 4;
    const int r0   = blockIdx.x * 128 + wv * 16;   // this wave's 16 rows

    // ---- issue ALL A loads first: in flight during staging+barrier ----
    const float* __restrict__ arow = X + (size_t)(r0 + col) * 128 + quad * 8;
    float4 f[4][2];
#pragma unroll
    for (int kt = 0; kt < 4; ++kt) {
        f[kt][0] = *(const float4*)(arow + kt * 32);
        f[kt][1] = *(const float4*)(arow + kt * 32 + 4);
    }

    // ---- stage both weight matrices into LDS (swizzled slots) ----
#pragma unroll
    for (int i = 0; i < 8; ++i) {
        int v = i * 512 + tid;           // 0..4095 uint4 tiles
        int mat = v >> 11;
        int r = (v >> 4) & 127;
        int s = v & 15;
        const unsigned short* src = (mat ? WtB : WtA) + r * 128 + s * 8;
        uint4 d = *(const uint4*)src;
        *(uint4*)&wl[mat * 16384 + r * 128 + ((s ^ (r & 7)) << 3)] = d;
    }
    __syncthreads();

    frag_u a[4];
#pragma unroll
    for (int kt = 0; kt < 4; ++kt) a[kt].v = cvt8(f[kt][0], f[kt][1]);

    f32x4v accA[8], accB[8];
#pragma unroll
    for (int nt = 0; nt < 8; ++nt) {
        accA[nt] = (f32x4v){0.f, 0.f, 0.f, 0.f};
        accB[nt] = (f32x4v){0.f, 0.f, 0.f, 0.f};
    }

    const int x7 = col & 7;
#pragma unroll
    for (int kt = 0; kt < 4; ++kt) {
#pragma unroll
        for (int nt = 0; nt < 8; ++nt) {
            int off = nt * 2048 + col * 128 + ((((kt << 2) | quad) ^ x7) << 3);
            frag_u b0, b1;
            b0.u = *(const uint4*)&wl[off];
            b1.u = *(const uint4*)&wl[16384 + off];
            accA[nt] = __builtin_amdgcn_mfma_f32_16x16x32_bf16(a[kt].v, b0.v, accA[nt], 0, 0, 0);
            accB[nt] = __builtin_amdgcn_mfma_f32_16x16x32_bf16(a[kt].v, b1.v, accB[nt], 0, 0, 0);
        }
    }

    // epilogue: C row = r0 + quad*4 + r; col c = nt*16 + col
#pragma unroll
    for (int r = 0; r < 4; ++r) {
        int row = r0 + quad * 4 + r;
        int n = row >> 8;
        int si = row & 255;
#pragma unroll
        for (int nt = 0; nt < 8; ++nt) {
            int c = nt * 16 + col;
            int h = c >> 5, d = c & 31;
            size_t nh = (size_t)(n * HH + h);
            if (pp == 0) {
                float qv = accA[nt][r] * 0.17677669529663687f;  // 1/sqrt(32)
                q_ws[(nh * QDIM + si) * DD + d] = f2bf(qv);
                float s = 1.0f / (1.0f + __expf(-accB[nt][r]));
                g_ws[(nh * QDIM + si) * DD + d] = f2bf(s);
            } else {
                k_ws[(nh * QDIM + si) * DD + d] = f2bf(accA[nt][r]);
                // V stored TRANSPOSED: [n][h][d][key]
                v_ws[(nh * DD + d) * QDIM + si] = f2bf(accB[nt][r]);
            }
        }
    }
}

// =====================================================================
// Kernel 2: MFMA attention, round 5: block per (n,h), grid 1024.
//  - XCD-grouped by h (128 consecutive-n blocks per XCD share tri[h]).
//  - V staged to LDS ONCE (r4 source-swizzled pattern), then 4 query
//    chunks processed in a fully-unrolled, BARRIER-FREE loop: Pl rows
//    are wave-private (same-wave DS ops are in-order), K fragment
//    addresses repeat each iteration (L1-resident after iter 0), and
//    the scheduler can hoist iter i+1 bias/Q loads over iter i PV.
// =====================================================================
__global__ __launch_bounds__(256, 3) void attn_kernel(
    const unsigned short* __restrict__ q_ws, const unsigned short* __restrict__ k_ws,
    const unsigned short* __restrict__ v_ws, const unsigned short* __restrict__ g_ws,
    const float* __restrict__ tri, const float* __restrict__ mb,
    unsigned short* __restrict__ o_ws)
{
    __shared__ unsigned short vl[32 * 256];   // 16 KB, swizzled V^T
    __shared__ unsigned short Pl[64 * 264];   // P [q][key], 33.8 KB

    const int tid = threadIdx.x;
    const int b = blockIdx.x;                 // 0..1023
    const int L = (b & 7) * 128 + (b >> 3);   // XCD chunk of 128 (bijective)
    const int h = L >> 8;                     // one h per XCD chunk
    const int n = L & 255;
    const size_t base = (size_t)(n * HH + h) * QDIM * DD;

    const int wv   = tid >> 6;
    const int lane = tid & 63;
    const int col  = lane & 15;
    const int quad = lane >> 4;
    const int x7   = col & 7;

    // ---- issue V stage loads now; LDS-write deferred to after softmax0
    frag_u vreg[4];
    const unsigned short* __restrict__ vsrc = v_ws + base;
#pragma unroll
    for (int j = 0; j < 4; ++j) {
        int idx = (wv * 4 + j) * 64 + lane;   // 0..1023 16B tiles
        int d = idx >> 5, s = idx & 31;
        vreg[j].u = *(const uint4*)(vsrc + d * 256 + ((s ^ (d & 7)) << 3));
    }

#pragma unroll
    for (int qc = 0; qc < 4; ++qc) {
        const int qg = qc * 64 + wv * 16 + col;

        // bias prefetch: 32 independent fp32 loads, consumed as MFMA C
        f32x4v bias[16];
#pragma unroll
        for (int mt = 0; mt < 16; ++mt) {
            int k0 = mt * 16 + quad * 4;
            float4 t4 = *(const float4*)&tri[((size_t)(h * 256 + qg)) * 256 + k0];
            float4 m4 = *(const float4*)&mb[n * 256 + k0];
            bias[mt][0] = t4.x + m4.x; bias[mt][1] = t4.y + m4.y;
            bias[mt][2] = t4.z + m4.z; bias[mt][3] = t4.w + m4.w;
        }

        frag_u bq;
        bq.u = *(const uint4*)(q_ws + base + (size_t)qg * DD + quad * 8);

        f32x4v acc[16];
#pragma unroll
        for (int mt = 0; mt < 16; ++mt) {
            frag_u ak;
            ak.u = *(const uint4*)(k_ws + base + (size_t)(mt * 16 + col) * DD + quad * 8);
            acc[mt] = __builtin_amdgcn_mfma_f32_16x16x32_bf16(ak.v, bq.v, bias[mt], 0, 0, 0);
        }

        float mx = -1e30f;
#pragma unroll
        for (int mt = 0; mt < 16; ++mt)
#pragma unroll
            for (int r = 0; r < 4; ++r) mx = fmaxf(mx, acc[mt][r]);
        mx = fmaxf(mx, __shfl_xor(mx, 16));
        mx = fmaxf(mx, __shfl_xor(mx, 32));

        float sum = 0.f;
#pragma unroll
        for (int mt = 0; mt < 16; ++mt)
#pragma unroll
            for (int r = 0; r < 4; ++r) {
                float e = __expf(acc[mt][r] - mx);
                acc[mt][r] = e;
                sum += e;
            }
        sum += __shfl_xor(sum, 16);
        sum += __shfl_xor(sum, 32);
        float inv = 1.0f / sum;   // every lane holds inv for q-row == its col

        // ---- V stage writes + the ONLY barrier (first iteration)
        if (qc == 0) {
#pragma unroll
            for (int j = 0; j < 4; ++j) {
                int idx = (wv * 4 + j) * 64 + lane;
                *(uint4*)&vl[idx << 3] = vreg[j].u;   // linear dest
            }
            __syncthreads();
        }

        // P -> LDS (wave-private rows, reused every iteration)
#pragma unroll
        for (int mt = 0; mt < 16; ++mt) {
            ushort4 pk;
            pk.x = f2bf(acc[mt][0]); pk.y = f2bf(acc[mt][1]);
            pk.z = f2bf(acc[mt][2]); pk.w = f2bf(acc[mt][3]);
            *(ushort4*)&Pl[(wv * 16 + col) * 264 + mt * 16 + quad * 4] = pk;
        }

        f32x4v o0 = {0.f, 0.f, 0.f, 0.f};
        f32x4v o1 = {0.f, 0.f, 0.f, 0.f};
#pragma unroll
        for (int kc = 0; kc < 8; ++kc) {
            int u0 = ((kc << 2) | quad) ^ x7;     // swizzled 16B slot
            frag_u ap, b0, b1;
            ap.u = *(const uint4*)&Pl[(wv * 16 + col) * 264 + kc * 32 + quad * 8];
            b0.u = *(const uint4*)&vl[(col << 8) + (u0 << 3)];
            b1.u = *(const uint4*)&vl[((16 + col) << 8) + (u0 << 3)];
            o0 = __builtin_amdgcn_mfma_f32_16x16x32_bf16(ap.v, b0.v, o0, 0, 0, 0);
            o1 = __builtin_amdgcn_mfma_f32_16x16x32_bf16(ap.v, b1.v, o1, 0, 0, 0);
        }

#pragma unroll
        for (int r = 0; r < 4; ++r) {
            int qi = quad * 4 + r;
            int qglob = qc * 64 + wv * 16 + qi;
            float iv = __shfl(inv, qi);   // lane qi holds q-row qi's inv
            size_t ob = (((size_t)(n * HH + h)) * QDIM + qglob) * DD;
            float g0 = bf2f(g_ws[ob + col]);
            o_ws[ob + col] = f2bf(o0[r] * iv * g0);
            float g1 = bf2f(g_ws[ob + 16 + col]);
            o_ws[ob + 16 + col] = f2bf(o1[r] * iv * g1);
        }
    }
}

// =====================================================================
// Kernel 3: MFMA out-projection. grid RROWS/64 = 1024, 256 thr.
// LDS-resident Wo (32 KB, swizzled) -> 4 blocks/CU for latency hiding.
// =====================================================================
__global__ __launch_bounds__(256, 4) void outproj_mfma(
    const unsigned short* __restrict__ o_ws, const unsigned short* __restrict__ wt,
    float* __restrict__ out)
{
    __shared__ unsigned short wl[16384];   // 32 KB swizzled Wo^T
    const int tid = threadIdx.x;           // 0..255
    const unsigned short* __restrict__ Wt = wt + 4 * 16384;

    const int wv   = tid >> 6;             // 0..3
    const int lane = tid & 63;
    const int col  = lane & 15;
    const int quad = lane >> 4;
    const int r0   = blockIdx.x * 64 + wv * 16;   // flattened (n,q)
    const int n    = r0 >> 8;                     // 64-row blocks stay in one n
    const int q0   = r0 & 255;

    // A loads first (in flight during staging+barrier)
    frag_u a[4];
#pragma unroll
    for (int kt = 0; kt < 4; ++kt)
        a[kt].u = *(const uint4*)(o_ws +
            ((size_t)(n * HH + kt) * QDIM + q0 + col) * DD + quad * 8);

    // stage Wo^T into LDS (swizzled): 2048 uint4 tiles, 8 per thread
#pragma unroll
    for (int i = 0; i < 8; ++i) {
        int v = i * 256 + tid;    // 0..2047
        int r = v >> 4;
        int s = v & 15;
        uint4 d = *(const uint4*)(Wt + r * 128 + s * 8);
        *(uint4*)&wl[r * 128 + ((s ^ (r & 7)) << 3)] = d;
    }
    __syncthreads();

    f32x4v acc[8];
#pragma unroll
    for (int nt = 0; nt < 8; ++nt)
        acc[nt] = (f32x4v){0.f, 0.f, 0.f, 0.f};

    const int x7 = col & 7;
#pragma unroll
    for (int kt = 0; kt < 4; ++kt) {
#pragma unroll
        for (int nt = 0; nt < 8; ++nt) {
            int off = nt * 2048 + col * 128 + ((((kt << 2) | quad) ^ x7) << 3);
            frag_u b;
            b.u = *(const uint4*)&wl[off];
            acc[nt] = __builtin_amdgcn_mfma_f32_16x16x32_bf16(a[kt].v, b.v, acc[nt], 0, 0, 0);
        }
    }

#pragma unroll
    for (int r = 0; r < 4; ++r) {
        size_t row = r0 + quad * 4 + r;
#pragma unroll
        for (int nt = 0; nt < 8; ++nt)
            out[row * 128 + nt * 16 + col] = acc[nt][r];
    }
}

// =====================================================================
extern "C" void kernel_launch(void* const* d_in, const int* in_sizes, int n_in,
                              void* d_out, int out_size, void* d_ws, size_t ws_size,
                              hipStream_t stream) {
    const float* qx  = (const float*)d_in[0];
    const float* kvx = (const float*)d_in[1];
    const float* tri = (const float*)d_in[2];
    const float* mb  = (const float*)d_in[3];
    // d_in[4] = mask (unused: mask_bias carries it in the reference path)
    const float* Wq  = (const float*)d_in[5];
    const float* Wk  = (const float*)d_in[6];
    const float* Wv  = (const float*)d_in[7];
    const float* Wg  = (const float*)d_in[8];
    const float* Wo  = (const float*)d_in[9];
    float* out = (float*)d_out;

    unsigned short* ws = (unsigned short*)d_ws;
    const size_t RC = (size_t)RROWS * 128;
    unsigned short* q_ws = ws;            // [n][h][q][32]
    unsigned short* k_ws = ws + RC;       // [n][h][k][32]
    unsigned short* v_ws = ws + 2 * RC;   // [n][h][d][key]  (transposed)
    unsigned short* g_ws = ws + 3 * RC;   // [n][h][q][32]
    unsigned short* o_ws = ws + 4 * RC;   // [n][h][q][32]
    unsigned short* wt   = ws + 5 * RC;   // 5 x [128][128] bf16 transposed weights

    prep_weights<<<dim3(40), 256, 0, stream>>>(Wq, Wk, Wv, Wg, Wo, wt);
    proj_mfma<<<dim3(RROWS / 128, 2), 512, 0, stream>>>(
        qx, kvx, wt, q_ws, k_ws, v_ws, g_ws);
    attn_kernel<<<dim3(1024), 256, 0, stream>>>(
        q_ws, k_ws, v_ws, g_ws, tri, mb, o_ws);
    outproj_mfma<<<dim3(RROWS / 64), 256, 0, stream>>>(o_ws, wt, out);
}

// Round 6
// 258.819 us; speedup vs baseline: 1.1581x; 1.1581x over previous
//
#include <hip/hip_runtime.h>
#include <hip/hip_bf16.h>

// Problem constants
#define NDIM 256   // outer n
#define QDIM 256   // q/k sequence
#define CDIM 128   // channels
#define HH 4       // heads
#define DD 32      // head dim
#define RROWS (NDIM * QDIM)  // 65536 flattened rows

// ---------- bf16 helpers (raw ushort storage, fp32 compute) ----------
__device__ __forceinline__ float bf2f(unsigned short u) {
    unsigned int x = ((unsigned int)u) << 16;
    return __uint_as_float(x);
}
__device__ __forceinline__ unsigned short f2bf(float f) {
    unsigned int x = __float_as_uint(f);
    unsigned int lsb = (x >> 16) & 1u;
    x += 0x7fffu + lsb;   // round-to-nearest-even
    return (unsigned short)(x >> 16);
}

// MFMA fragment types (gfx950: mfma_f32_16x16x32_bf16)
typedef __bf16 bf16x8v __attribute__((ext_vector_type(8)));
typedef float  f32x4v  __attribute__((ext_vector_type(4)));
union frag_u { uint4 u; bf16x8v v; };

__device__ __forceinline__ bf16x8v cvt8(float4 f0, float4 f1) {
    bf16x8v r;
    r[0] = (__bf16)f0.x; r[1] = (__bf16)f0.y; r[2] = (__bf16)f0.z; r[3] = (__bf16)f0.w;
    r[4] = (__bf16)f1.x; r[5] = (__bf16)f1.y; r[6] = (__bf16)f1.z; r[7] = (__bf16)f1.w;
    return r;
}

// =====================================================================
// Kernel 0: weight prep. 40 blocks (5 matrices x 8 k-chunks of 16).
// wt[p][n][k] = bf16(W_p[k][n])   (transposed so B-frags are contiguous)
// =====================================================================
__global__ __launch_bounds__(256, 1) void prep_weights(
    const float* __restrict__ Wq, const float* __restrict__ Wk,
    const float* __restrict__ Wv, const float* __restrict__ Wg,
    const float* __restrict__ Wo, unsigned short* __restrict__ wt)
{
    __shared__ unsigned short t[16][130];   // pad 130: conflict-free column reads
    const int p  = blockIdx.x >> 3;
    const int ch = blockIdx.x & 7;          // 16-row k-chunk
    const float* __restrict__ W = (p == 0) ? Wq : (p == 1) ? Wk :
                                  (p == 2) ? Wv : (p == 3) ? Wg : Wo;
    const int tid = threadIdx.x;
    for (int idx = tid; idx < 2048; idx += 256) {
        int k = idx >> 7, n = idx & 127;
        t[k][n] = f2bf(W[(ch * 16 + k) * 128 + n]);
    }
    __syncthreads();
    unsigned short* dst = wt + (size_t)p * 16384;
    for (int idx = tid; idx < 2048; idx += 256) {
        int n = idx >> 4, k = idx & 15;
        dst[n * 128 + ch * 16 + k] = t[k][n];   // Wt[n][k] = W[k][n]
    }
}

// =====================================================================
// Kernel 1: fused MFMA projections, round 6: ROLES INVERTED.
// grid (RROWS/64, 2), 512 thr (8 waves). Wave w owns output cols
// [16w,16w+16): its 8 B-frags (4kt x 2 matrices) live in 32 VGPRs,
// loaded ONCE from global wt (L2-hot, issued before staging).
// X staged per block as bf16 into 16 KB XOR-swizzled LDS.
// Inner loop: 16 ds_read_b128 + 32 MFMA per wave (was 64 reads/16 rows).
//   pp=0: X=qx  -> q (scaled) and g (sigmoid)   [n][h][q][32]
//   pp=1: X=kvx -> k [n][h][k][32], v TRANSPOSED [n][h][d][key]
// =====================================================================
__global__ __launch_bounds__(512, 4) void proj_mfma(
    const float* __restrict__ qx, const float* __restrict__ kvx,
    const unsigned short* __restrict__ wt,
    unsigned short* __restrict__ q_ws, unsigned short* __restrict__ k_ws,
    unsigned short* __restrict__ v_ws, unsigned short* __restrict__ g_ws)
{
    __shared__ unsigned short xl[64 * 128];    // 16 KB bf16 X tile, swizzled
    const int tid = threadIdx.x;               // 0..511
    const int pp = blockIdx.y;
    const float* __restrict__ X = pp ? kvx : qx;
    // pp=0: A-path = Wq (idx 0), B-path = Wg (idx 3)
    // pp=1: A-path = Wk (idx 1), B-path = Wv (idx 2)
    const unsigned short* __restrict__ WtA = wt + (size_t)(pp ? 1 : 0) * 16384;
    const unsigned short* __restrict__ WtB = wt + (size_t)(pp ? 2 : 3) * 16384;

    const int wv   = tid >> 6;     // 0..7 = this wave's nt (16-col slice)
    const int lane = tid & 63;
    const int col  = lane & 15;
    const int quad = lane >> 4;
    const int r0   = blockIdx.x * 64;

    // ---- B-frags from global wt into registers (issued first) ----
    frag_u bA[4], bB[4];
#pragma unroll
    for (int kt = 0; kt < 4; ++kt) {
        size_t boff = (size_t)(wv * 16 + col) * 128 + kt * 32 + quad * 8;
        bA[kt].u = *(const uint4*)(WtA + boff);
        bB[kt].u = *(const uint4*)(WtB + boff);
    }

    // ---- stage X rows r0..r0+63 as bf16 into LDS (XOR-swizzled) ----
#pragma unroll
    for (int i = 0; i < 2; ++i) {
        int idx = i * 512 + tid;       // 0..1023 = 64 rows x 16 slots
        int row = idx >> 4;
        int s   = idx & 15;
        const float* src = X + (size_t)(r0 + row) * 128 + s * 8;
        float4 f0 = *(const float4*)src;
        float4 f1 = *(const float4*)(src + 4);
        frag_u t; t.v = cvt8(f0, f1);
        *(uint4*)&xl[row * 128 + ((s ^ (row & 7)) << 3)] = t.u;
    }
    __syncthreads();

    f32x4v accA[4], accB[4];
#pragma unroll
    for (int mt = 0; mt < 4; ++mt) {
        accA[mt] = (f32x4v){0.f, 0.f, 0.f, 0.f};
        accB[mt] = (f32x4v){0.f, 0.f, 0.f, 0.f};
    }

    const int x7 = col & 7;
#pragma unroll
    for (int mt = 0; mt < 4; ++mt) {
        frag_u a[4];
#pragma unroll
        for (int kt = 0; kt < 4; ++kt)
            a[kt].u = *(const uint4*)&xl[(mt * 16 + col) * 128 +
                                         ((((kt << 2) | quad) ^ x7) << 3)];
#pragma unroll
        for (int kt = 0; kt < 4; ++kt) {
            accA[mt] = __builtin_amdgcn_mfma_f32_16x16x32_bf16(a[kt].v, bA[kt].v, accA[mt], 0, 0, 0);
            accB[mt] = __builtin_amdgcn_mfma_f32_16x16x32_bf16(a[kt].v, bB[kt].v, accB[mt], 0, 0, 0);
        }
    }

    // epilogue: C row = r0 + mt*16 + quad*4 + r; col c = wv*16 + col
    const int c = wv * 16 + col;
    const int h = c >> 5, d = c & 31;
#pragma unroll
    for (int mt = 0; mt < 4; ++mt) {
#pragma unroll
        for (int r = 0; r < 4; ++r) {
            int row = r0 + mt * 16 + quad * 4 + r;
            int n = row >> 8;
            int si = row & 255;
            size_t nh = (size_t)(n * HH + h);
            if (pp == 0) {
                float qv = accA[mt][r] * 0.17677669529663687f;  // 1/sqrt(32)
                q_ws[(nh * QDIM + si) * DD + d] = f2bf(qv);
                float s = 1.0f / (1.0f + __expf(-accB[mt][r]));
                g_ws[(nh * QDIM + si) * DD + d] = f2bf(s);
            } else {
                k_ws[(nh * QDIM + si) * DD + d] = f2bf(accA[mt][r]);
                // V stored TRANSPOSED: [n][h][d][key]
                v_ws[(nh * DD + d) * QDIM + si] = f2bf(accB[mt][r]);
            }
        }
    }
}

// =====================================================================
// Kernel 2: MFMA attention — EXACT round-4 version (measured 65.5 us).
// =====================================================================
__global__ __launch_bounds__(256, 3) void attn_kernel(
    const unsigned short* __restrict__ q_ws, const unsigned short* __restrict__ k_ws,
    const unsigned short* __restrict__ v_ws, const unsigned short* __restrict__ g_ws,
    const float* __restrict__ tri, const float* __restrict__ mb,
    unsigned short* __restrict__ o_ws)
{
    __shared__ unsigned short vl[32 * 256];   // 16 KB, swizzled content
    __shared__ unsigned short Pl[64 * 264];   // P [q][key], 33.8 KB

    const int tid = threadIdx.x;
    const int b = blockIdx.x;
    const int L = (b & 7) * 512 + (b >> 3);   // XCD-contiguous logical id
    const int qc = L & 3;          // 64-query chunk
    const int n  = (L >> 2) & 255;
    const int h  = L >> 10;
    const size_t base  = (size_t)(n * HH + h) * QDIM * DD;   // q,k: [seq][32]
    const size_t vbase = (size_t)(n * HH + h) * DD * QDIM;   // v^T: [32][seq]

    const int wv   = tid >> 6;
    const int lane = tid & 63;
    const int col  = lane & 15;
    const int quad = lane >> 4;
    const int x7   = col & 7;
    const int qg   = qc * 64 + wv * 16 + col;

    // ---- issue V stage loads FIRST (fire-and-forget; land after softmax)
    frag_u vreg[4];
    const unsigned short* __restrict__ vsrc = v_ws + vbase;
#pragma unroll
    for (int j = 0; j < 4; ++j) {
        int idx = (wv * 4 + j) * 64 + lane;   // 0..1023
        int d = idx >> 5, s = idx & 31;
        vreg[j].u = *(const uint4*)(vsrc + d * 256 + ((s ^ (d & 7)) << 3));
    }

    // ---- bias prefetch: 32 independent fp32 loads, consumed as MFMA C
    f32x4v bias[16];
#pragma unroll
    for (int mt = 0; mt < 16; ++mt) {
        int k0 = mt * 16 + quad * 4;
        float4 t4 = *(const float4*)&tri[((size_t)(h * 256 + qg)) * 256 + k0];
        float4 m4 = *(const float4*)&mb[n * 256 + k0];
        bias[mt][0] = t4.x + m4.x; bias[mt][1] = t4.y + m4.y;
        bias[mt][2] = t4.z + m4.z; bias[mt][3] = t4.w + m4.w;
    }

    frag_u bq;
    bq.u = *(const uint4*)(q_ws + base + (size_t)qg * DD + quad * 8);

    f32x4v acc[16];
#pragma unroll
    for (int mt = 0; mt < 16; ++mt) {
        frag_u ak;
        ak.u = *(const uint4*)(k_ws + base + (size_t)(mt * 16 + col) * DD + quad * 8);
        acc[mt] = __builtin_amdgcn_mfma_f32_16x16x32_bf16(ak.v, bq.v, bias[mt], 0, 0, 0);
    }

    float mx = -1e30f;
#pragma unroll
    for (int mt = 0; mt < 16; ++mt)
#pragma unroll
        for (int r = 0; r < 4; ++r) mx = fmaxf(mx, acc[mt][r]);
    mx = fmaxf(mx, __shfl_xor(mx, 16));
    mx = fmaxf(mx, __shfl_xor(mx, 32));

    float sum = 0.f;
#pragma unroll
    for (int mt = 0; mt < 16; ++mt)
#pragma unroll
        for (int r = 0; r < 4; ++r) {
            float e = __expf(acc[mt][r] - mx);
            acc[mt][r] = e;
            sum += e;
        }
    sum += __shfl_xor(sum, 16);
    sum += __shfl_xor(sum, 32);
    float inv = 1.0f / sum;   // every lane holds inv for q-row == its col

    // P -> LDS (wave-private rows; acc[mt][r] = S[key=mt*16+quad*4+r][q=col])
#pragma unroll
    for (int mt = 0; mt < 16; ++mt) {
        ushort4 pk;
        pk.x = f2bf(acc[mt][0]); pk.y = f2bf(acc[mt][1]);
        pk.z = f2bf(acc[mt][2]); pk.w = f2bf(acc[mt][3]);
        *(ushort4*)&Pl[(wv * 16 + col) * 264 + mt * 16 + quad * 4] = pk;
    }

    // ---- V stage writes (global loads have had QK^T+softmax to land)
#pragma unroll
    for (int j = 0; j < 4; ++j) {
        int idx = (wv * 4 + j) * 64 + lane;
        *(uint4*)&vl[idx << 3] = vreg[j].u;   // linear dest: idx*16 bytes
    }
    __syncthreads();   // vl is read cross-wave below

    f32x4v o0 = {0.f, 0.f, 0.f, 0.f};
    f32x4v o1 = {0.f, 0.f, 0.f, 0.f};
#pragma unroll
    for (int kc = 0; kc < 8; ++kc) {
        int u0 = ((kc << 2) | quad) ^ x7;     // swizzled 16B slot
        frag_u ap, b0, b1;
        ap.u = *(const uint4*)&Pl[(wv * 16 + col) * 264 + kc * 32 + quad * 8];
        b0.u = *(const uint4*)&vl[(col << 8) + (u0 << 3)];
        b1.u = *(const uint4*)&vl[((16 + col) << 8) + (u0 << 3)];
        o0 = __builtin_amdgcn_mfma_f32_16x16x32_bf16(ap.v, b0.v, o0, 0, 0, 0);
        o1 = __builtin_amdgcn_mfma_f32_16x16x32_bf16(ap.v, b1.v, o1, 0, 0, 0);
    }

#pragma unroll
    for (int r = 0; r < 4; ++r) {
        int qi = quad * 4 + r;
        int qglob = qc * 64 + wv * 16 + qi;
        float iv = __shfl(inv, qi);   // lane qi holds q-row qi's inv
        size_t ob = (((size_t)(n * HH + h)) * QDIM + qglob) * DD;
        float g0 = bf2f(g_ws[ob + col]);
        o_ws[ob + col] = f2bf(o0[r] * iv * g0);
        float g1 = bf2f(g_ws[ob + 16 + col]);
        o_ws[ob + 16 + col] = f2bf(o1[r] * iv * g1);
    }
}

// =====================================================================
// Kernel 3: MFMA out-projection, round 6: same role inversion.
// grid RROWS/64 = 1024, 512 thr. Wave w owns cols [16w,16w+16):
// 4 B-frags in 16 VGPRs from global wt; o staged to 16 KB swizzled LDS.
// =====================================================================
__global__ __launch_bounds__(512, 4) void outproj_mfma(
    const unsigned short* __restrict__ o_ws, const unsigned short* __restrict__ wt,
    float* __restrict__ out)
{
    __shared__ unsigned short xl[64 * 128];   // 16 KB bf16 o tile, swizzled
    const int tid = threadIdx.x;              // 0..511
    const unsigned short* __restrict__ Wt = wt + 4 * 16384;

    const int wv   = tid >> 6;                // 0..7 = nt
    const int lane = tid & 63;
    const int col  = lane & 15;
    const int quad = lane >> 4;
    const int r0   = blockIdx.x * 64;         // flattened (n,q); 64 | 256
    const int n    = r0 >> 8;
    const int q0   = r0 & 255;

    // ---- B-frags from global wt into registers (issued first) ----
    frag_u bO[4];
#pragma unroll
    for (int kt = 0; kt < 4; ++kt)
        bO[kt].u = *(const uint4*)(Wt + (size_t)(wv * 16 + col) * 128 + kt * 32 + quad * 8);

    // ---- stage o rows (bf16, channel c = h*32+d) into swizzled LDS ----
#pragma unroll
    for (int i = 0; i < 2; ++i) {
        int idx = i * 512 + tid;       // 0..1023 = 64 rows x 16 slots
        int row = idx >> 4;
        int s   = idx & 15;            // slot -> channels s*8..s*8+7
        int h   = s >> 2;
        int d   = (s & 3) << 3;
        uint4 v = *(const uint4*)(o_ws +
            ((size_t)(n * HH + h) * QDIM + q0 + row) * DD + d);
        *(uint4*)&xl[row * 128 + ((s ^ (row & 7)) << 3)] = v;
    }
    __syncthreads();

    f32x4v acc[4];
#pragma unroll
    for (int mt = 0; mt < 4; ++mt)
        acc[mt] = (f32x4v){0.f, 0.f, 0.f, 0.f};

    const int x7 = col & 7;
#pragma unroll
    for (int mt = 0; mt < 4; ++mt) {
        frag_u a[4];
#pragma unroll
        for (int kt = 0; kt < 4; ++kt)
            a[kt].u = *(const uint4*)&xl[(mt * 16 + col) * 128 +
                                         ((((kt << 2) | quad) ^ x7) << 3)];
#pragma unroll
        for (int kt = 0; kt < 4; ++kt)
            acc[mt] = __builtin_amdgcn_mfma_f32_16x16x32_bf16(a[kt].v, bO[kt].v, acc[mt], 0, 0, 0);
    }

#pragma unroll
    for (int mt = 0; mt < 4; ++mt)
#pragma unroll
        for (int r = 0; r < 4; ++r) {
            size_t row = r0 + mt * 16 + quad * 4 + r;
            out[row * 128 + wv * 16 + col] = acc[mt][r];
        }
}

// =====================================================================
extern "C" void kernel_launch(void* const* d_in, const int* in_sizes, int n_in,
                              void* d_out, int out_size, void* d_ws, size_t ws_size,
                              hipStream_t stream) {
    const float* qx  = (const float*)d_in[0];
    const float* kvx = (const float*)d_in[1];
    const float* tri = (const float*)d_in[2];
    const float* mb  = (const float*)d_in[3];
    // d_in[4] = mask (unused: mask_bias carries it in the reference path)
    const float* Wq  = (const float*)d_in[5];
    const float* Wk  = (const float*)d_in[6];
    const float* Wv  = (const float*)d_in[7];
    const float* Wg  = (const float*)d_in[8];
    const float* Wo  = (const float*)d_in[9];
    float* out = (float*)d_out;

    unsigned short* ws = (unsigned short*)d_ws;
    const size_t RC = (size_t)RROWS * 128;
    unsigned short* q_ws = ws;            // [n][h][q][32]
    unsigned short* k_ws = ws + RC;       // [n][h][k][32]
    unsigned short* v_ws = ws + 2 * RC;   // [n][h][d][key]  (transposed)
    unsigned short* g_ws = ws + 3 * RC;   // [n][h][q][32]
    unsigned short* o_ws = ws + 4 * RC;   // [n][h][q][32]
    unsigned short* wt   = ws + 5 * RC;   // 5 x [128][128] bf16 transposed weights

    prep_weights<<<dim3(40), 256, 0, stream>>>(Wq, Wk, Wv, Wg, Wo, wt);
    proj_mfma<<<dim3(RROWS / 64, 2), 512, 0, stream>>>(
        qx, kvx, wt, q_ws, k_ws, v_ws, g_ws);
    attn_kernel<<<dim3(4096), 256, 0, stream>>>(
        q_ws, k_ws, v_ws, g_ws, tri, mb, o_ws);
    outproj_mfma<<<dim3(RROWS / 64), 512, 0, stream>>>(o_ws, wt, out);
}

// Round 7
// 235.683 us; speedup vs baseline: 1.2718x; 1.0982x over previous
//
#include <hip/hip_runtime.h>
#include <hip/hip_bf16.h>

// Problem constants
#define NDIM 256   // outer n
#define QDIM 256   // q/k sequence
#define CDIM 128   // channels
#define HH 4       // heads
#define DD 32      // head dim
#define RROWS (NDIM * QDIM)  // 65536 flattened rows

// ---------- bf16 helpers (raw ushort storage, fp32 compute) ----------
__device__ __forceinline__ float bf2f(unsigned short u) {
    unsigned int x = ((unsigned int)u) << 16;
    return __uint_as_float(x);
}
__device__ __forceinline__ unsigned short f2bf(float f) {
    unsigned int x = __float_as_uint(f);
    unsigned int lsb = (x >> 16) & 1u;
    x += 0x7fffu + lsb;   // round-to-nearest-even
    return (unsigned short)(x >> 16);
}

// MFMA fragment types (gfx950: mfma_f32_16x16x32_bf16)
typedef __bf16 bf16x8v __attribute__((ext_vector_type(8)));
typedef float  f32x4v  __attribute__((ext_vector_type(4)));
union frag_u { uint4 u; bf16x8v v; };

__device__ __forceinline__ bf16x8v cvt8(float4 f0, float4 f1) {
    bf16x8v r;
    r[0] = (__bf16)f0.x; r[1] = (__bf16)f0.y; r[2] = (__bf16)f0.z; r[3] = (__bf16)f0.w;
    r[4] = (__bf16)f1.x; r[5] = (__bf16)f1.y; r[6] = (__bf16)f1.z; r[7] = (__bf16)f1.w;
    return r;
}

// =====================================================================
// Kernel 0: weight prep. 40 blocks (5 matrices x 8 k-chunks of 16).
// wt[p][n][k] = bf16(W_p[k][n])   (transposed so B-frags are contiguous)
// =====================================================================
__global__ __launch_bounds__(256, 1) void prep_weights(
    const float* __restrict__ Wq, const float* __restrict__ Wk,
    const float* __restrict__ Wv, const float* __restrict__ Wg,
    const float* __restrict__ Wo, unsigned short* __restrict__ wt)
{
    __shared__ unsigned short t[16][130];   // pad 130: conflict-free column reads
    const int p  = blockIdx.x >> 3;
    const int ch = blockIdx.x & 7;          // 16-row k-chunk
    const float* __restrict__ W = (p == 0) ? Wq : (p == 1) ? Wk :
                                  (p == 2) ? Wv : (p == 3) ? Wg : Wo;
    const int tid = threadIdx.x;
    for (int idx = tid; idx < 2048; idx += 256) {
        int k = idx >> 7, n = idx & 127;
        t[k][n] = f2bf(W[(ch * 16 + k) * 128 + n]);
    }
    __syncthreads();
    unsigned short* dst = wt + (size_t)p * 16384;
    for (int idx = tid; idx < 2048; idx += 256) {
        int n = idx >> 4, k = idx & 15;
        dst[n * 128 + ch * 16 + k] = t[k][n];   // Wt[n][k] = W[k][n]
    }
}

// =====================================================================
// Kernel 1: fused MFMA projections, round 7.
// Same compute structure as round 6 (roles inverted: B-frags in regs,
// X staged in 16 KB swizzled LDS). NEW: epilogue goes through an LDS
// bounce so ALL global stores are coalesced 16B (was 32 scalar 2B
// stores/thread, the v^T path fanning 16 transactions per instr).
//   pp=0: X=qx  -> q (scaled) and g (sigmoid)   [n][h][q][32]
//   pp=1: X=kvx -> k [n][h][k][32], v TRANSPOSED [n][h][d][key]
// =====================================================================
__global__ __launch_bounds__(512, 4) void proj_mfma(
    const float* __restrict__ qx, const float* __restrict__ kvx,
    const unsigned short* __restrict__ wt,
    unsigned short* __restrict__ q_ws, unsigned short* __restrict__ k_ws,
    unsigned short* __restrict__ v_ws, unsigned short* __restrict__ g_ws)
{
    __shared__ unsigned short xl[64 * 128];    // 16 KB: X tile, then bounce
    const int tid = threadIdx.x;               // 0..511
    const int pp = blockIdx.y;
    const float* __restrict__ X = pp ? kvx : qx;
    // pp=0: A-path = Wq (idx 0), B-path = Wg (idx 3)
    // pp=1: A-path = Wk (idx 1), B-path = Wv (idx 2)
    const unsigned short* __restrict__ WtA = wt + (size_t)(pp ? 1 : 0) * 16384;
    const unsigned short* __restrict__ WtB = wt + (size_t)(pp ? 2 : 3) * 16384;

    const int wv   = tid >> 6;     // 0..7 = this wave's nt (16-col slice)
    const int lane = tid & 63;
    const int col  = lane & 15;
    const int quad = lane >> 4;
    const int r0   = blockIdx.x * 64;
    const int n    = r0 >> 8;
    const int q0   = r0 & 255;

    // ---- B-frags from global wt into registers (issued first) ----
    frag_u bA[4], bB[4];
#pragma unroll
    for (int kt = 0; kt < 4; ++kt) {
        size_t boff = (size_t)(wv * 16 + col) * 128 + kt * 32 + quad * 8;
        bA[kt].u = *(const uint4*)(WtA + boff);
        bB[kt].u = *(const uint4*)(WtB + boff);
    }

    // ---- stage X rows r0..r0+63 as bf16 into LDS (XOR-swizzled) ----
#pragma unroll
    for (int i = 0; i < 2; ++i) {
        int idx = i * 512 + tid;       // 0..1023 = 64 rows x 16 slots
        int row = idx >> 4;
        int s   = idx & 15;
        const float* src = X + (size_t)(r0 + row) * 128 + s * 8;
        float4 f0 = *(const float4*)src;
        float4 f1 = *(const float4*)(src + 4);
        frag_u t; t.v = cvt8(f0, f1);
        *(uint4*)&xl[row * 128 + ((s ^ (row & 7)) << 3)] = t.u;
    }
    __syncthreads();

    f32x4v accA[4], accB[4];
#pragma unroll
    for (int mt = 0; mt < 4; ++mt) {
        accA[mt] = (f32x4v){0.f, 0.f, 0.f, 0.f};
        accB[mt] = (f32x4v){0.f, 0.f, 0.f, 0.f};
    }

    const int x7 = col & 7;
#pragma unroll
    for (int mt = 0; mt < 4; ++mt) {
        frag_u a[4];
#pragma unroll
        for (int kt = 0; kt < 4; ++kt)
            a[kt].u = *(const uint4*)&xl[(mt * 16 + col) * 128 +
                                         ((((kt << 2) | quad) ^ x7) << 3)];
#pragma unroll
        for (int kt = 0; kt < 4; ++kt) {
            accA[mt] = __builtin_amdgcn_mfma_f32_16x16x32_bf16(a[kt].v, bA[kt].v, accA[mt], 0, 0, 0);
            accB[mt] = __builtin_amdgcn_mfma_f32_16x16x32_bf16(a[kt].v, bB[kt].v, accB[mt], 0, 0, 0);
        }
    }

    // ================= epilogue via LDS bounce (coalesced stores) ======
    const int c = wv * 16 + col;               // this thread's output col
    __syncthreads();                           // all A-reads of xl done

    // ---- pass A: accA -> q (scaled) or k (raw), layout [n][h][q][32]
#pragma unroll
    for (int mt = 0; mt < 4; ++mt)
#pragma unroll
        for (int r = 0; r < 4; ++r) {
            int lr = mt * 16 + quad * 4 + r;
            float v = pp ? accA[mt][r] : accA[mt][r] * 0.17677669529663687f;
            xl[lr * 128 + (c ^ ((lr & 7) << 4))] = f2bf(v);
        }
    __syncthreads();
    {
        unsigned short* dst = pp ? k_ws : q_ws;
#pragma unroll
        for (int i = 0; i < 2; ++i) {
            int t = i * 512 + tid;     // 0..1023 = 64 rows x 16 slots
            int lr = t >> 4;
            int s  = t & 15;
            uint4 v = *(const uint4*)&xl[lr * 128 + ((s ^ ((lr & 7) << 1)) << 3)];
            int h = s >> 2, d0 = (s & 3) << 3;
            *(uint4*)(dst + ((size_t)(n * HH + h) * QDIM + q0 + lr) * DD + d0) = v;
        }
    }
    __syncthreads();

    // ---- pass B: accB -> g (sigmoid, [n][h][q][32]) or v^T ([n][h][d][key])
    if (pp == 0) {
#pragma unroll
        for (int mt = 0; mt < 4; ++mt)
#pragma unroll
            for (int r = 0; r < 4; ++r) {
                int lr = mt * 16 + quad * 4 + r;
                float s = 1.0f / (1.0f + __expf(-accB[mt][r]));
                xl[lr * 128 + (c ^ ((lr & 7) << 4))] = f2bf(s);
            }
        __syncthreads();
#pragma unroll
        for (int i = 0; i < 2; ++i) {
            int t = i * 512 + tid;
            int lr = t >> 4;
            int s  = t & 15;
            uint4 v = *(const uint4*)&xl[lr * 128 + ((s ^ ((lr & 7) << 1)) << 3)];
            int h = s >> 2, d0 = (s & 3) << 3;
            *(uint4*)(g_ws + ((size_t)(n * HH + h) * QDIM + q0 + lr) * DD + d0) = v;
        }
    } else {
        // transposed bounce: xlT[c][row], row bits 3..5 XORed by c&7 so
        // both b16 writes and b128 reads spread across banks.
#pragma unroll
        for (int mt = 0; mt < 4; ++mt)
#pragma unroll
            for (int r = 0; r < 4; ++r) {
                int lr = mt * 16 + quad * 4 + r;
                xl[c * 64 + (lr ^ ((c & 7) << 3))] = f2bf(accB[mt][r]);
            }
        __syncthreads();
#pragma unroll
        for (int i = 0; i < 2; ++i) {
            int t = i * 512 + tid;     // 0..1023 = 128 cols x 8 key-chunks
            int cc = t >> 3;
            int chunk = t & 7;
            uint4 v = *(const uint4*)&xl[cc * 64 + ((chunk ^ (cc & 7)) << 3)];
            int h = cc >> 5, d = cc & 31;
            *(uint4*)(v_ws + ((size_t)(n * HH + h) * DD + d) * QDIM + q0 + chunk * 8) = v;
        }
    }
}

// =====================================================================
// Kernel 2: MFMA attention — EXACT round-4/6 version (measured ~65.5 us).
// =====================================================================
__global__ __launch_bounds__(256, 3) void attn_kernel(
    const unsigned short* __restrict__ q_ws, const unsigned short* __restrict__ k_ws,
    const unsigned short* __restrict__ v_ws, const unsigned short* __restrict__ g_ws,
    const float* __restrict__ tri, const float* __restrict__ mb,
    unsigned short* __restrict__ o_ws)
{
    __shared__ unsigned short vl[32 * 256];   // 16 KB, swizzled content
    __shared__ unsigned short Pl[64 * 264];   // P [q][key], 33.8 KB

    const int tid = threadIdx.x;
    const int b = blockIdx.x;
    const int L = (b & 7) * 512 + (b >> 3);   // XCD-contiguous logical id
    const int qc = L & 3;          // 64-query chunk
    const int n  = (L >> 2) & 255;
    const int h  = L >> 10;
    const size_t base  = (size_t)(n * HH + h) * QDIM * DD;   // q,k: [seq][32]
    const size_t vbase = (size_t)(n * HH + h) * DD * QDIM;   // v^T: [32][seq]

    const int wv   = tid >> 6;
    const int lane = tid & 63;
    const int col  = lane & 15;
    const int quad = lane >> 4;
    const int x7   = col & 7;
    const int qg   = qc * 64 + wv * 16 + col;

    // ---- issue V stage loads FIRST (fire-and-forget; land after softmax)
    frag_u vreg[4];
    const unsigned short* __restrict__ vsrc = v_ws + vbase;
#pragma unroll
    for (int j = 0; j < 4; ++j) {
        int idx = (wv * 4 + j) * 64 + lane;   // 0..1023
        int d = idx >> 5, s = idx & 31;
        vreg[j].u = *(const uint4*)(vsrc + d * 256 + ((s ^ (d & 7)) << 3));
    }

    // ---- bias prefetch: 32 independent fp32 loads, consumed as MFMA C
    f32x4v bias[16];
#pragma unroll
    for (int mt = 0; mt < 16; ++mt) {
        int k0 = mt * 16 + quad * 4;
        float4 t4 = *(const float4*)&tri[((size_t)(h * 256 + qg)) * 256 + k0];
        float4 m4 = *(const float4*)&mb[n * 256 + k0];
        bias[mt][0] = t4.x + m4.x; bias[mt][1] = t4.y + m4.y;
        bias[mt][2] = t4.z + m4.z; bias[mt][3] = t4.w + m4.w;
    }

    frag_u bq;
    bq.u = *(const uint4*)(q_ws + base + (size_t)qg * DD + quad * 8);

    f32x4v acc[16];
#pragma unroll
    for (int mt = 0; mt < 16; ++mt) {
        frag_u ak;
        ak.u = *(const uint4*)(k_ws + base + (size_t)(mt * 16 + col) * DD + quad * 8);
        acc[mt] = __builtin_amdgcn_mfma_f32_16x16x32_bf16(ak.v, bq.v, bias[mt], 0, 0, 0);
    }

    float mx = -1e30f;
#pragma unroll
    for (int mt = 0; mt < 16; ++mt)
#pragma unroll
        for (int r = 0; r < 4; ++r) mx = fmaxf(mx, acc[mt][r]);
    mx = fmaxf(mx, __shfl_xor(mx, 16));
    mx = fmaxf(mx, __shfl_xor(mx, 32));

    float sum = 0.f;
#pragma unroll
    for (int mt = 0; mt < 16; ++mt)
#pragma unroll
        for (int r = 0; r < 4; ++r) {
            float e = __expf(acc[mt][r] - mx);
            acc[mt][r] = e;
            sum += e;
        }
    sum += __shfl_xor(sum, 16);
    sum += __shfl_xor(sum, 32);
    float inv = 1.0f / sum;   // every lane holds inv for q-row == its col

    // P -> LDS (wave-private rows; acc[mt][r] = S[key=mt*16+quad*4+r][q=col])
#pragma unroll
    for (int mt = 0; mt < 16; ++mt) {
        ushort4 pk;
        pk.x = f2bf(acc[mt][0]); pk.y = f2bf(acc[mt][1]);
        pk.z = f2bf(acc[mt][2]); pk.w = f2bf(acc[mt][3]);
        *(ushort4*)&Pl[(wv * 16 + col) * 264 + mt * 16 + quad * 4] = pk;
    }

    // ---- V stage writes (global loads have had QK^T+softmax to land)
#pragma unroll
    for (int j = 0; j < 4; ++j) {
        int idx = (wv * 4 + j) * 64 + lane;
        *(uint4*)&vl[idx << 3] = vreg[j].u;   // linear dest: idx*16 bytes
    }
    __syncthreads();   // vl is read cross-wave below

    f32x4v o0 = {0.f, 0.f, 0.f, 0.f};
    f32x4v o1 = {0.f, 0.f, 0.f, 0.f};
#pragma unroll
    for (int kc = 0; kc < 8; ++kc) {
        int u0 = ((kc << 2) | quad) ^ x7;     // swizzled 16B slot
        frag_u ap, b0, b1;
        ap.u = *(const uint4*)&Pl[(wv * 16 + col) * 264 + kc * 32 + quad * 8];
        b0.u = *(const uint4*)&vl[(col << 8) + (u0 << 3)];
        b1.u = *(const uint4*)&vl[((16 + col) << 8) + (u0 << 3)];
        o0 = __builtin_amdgcn_mfma_f32_16x16x32_bf16(ap.v, b0.v, o0, 0, 0, 0);
        o1 = __builtin_amdgcn_mfma_f32_16x16x32_bf16(ap.v, b1.v, o1, 0, 0, 0);
    }

#pragma unroll
    for (int r = 0; r < 4; ++r) {
        int qi = quad * 4 + r;
        int qglob = qc * 64 + wv * 16 + qi;
        float iv = __shfl(inv, qi);   // lane qi holds q-row qi's inv
        size_t ob = (((size_t)(n * HH + h)) * QDIM + qglob) * DD;
        float g0 = bf2f(g_ws[ob + col]);
        o_ws[ob + col] = f2bf(o0[r] * iv * g0);
        float g1 = bf2f(g_ws[ob + 16 + col]);
        o_ws[ob + 16 + col] = f2bf(o1[r] * iv * g1);
    }
}

// =====================================================================
// Kernel 3: MFMA out-projection — EXACT round-6 version.
// grid RROWS/64 = 1024, 512 thr. Wave w owns cols [16w,16w+16):
// 4 B-frags in 16 VGPRs from global wt; o staged to 16 KB swizzled LDS.
// =====================================================================
__global__ __launch_bounds__(512, 4) void outproj_mfma(
    const unsigned short* __restrict__ o_ws, const unsigned short* __restrict__ wt,
    float* __restrict__ out)
{
    __shared__ unsigned short xl[64 * 128];   // 16 KB bf16 o tile, swizzled
    const int tid = threadIdx.x;              // 0..511
    const unsigned short* __restrict__ Wt = wt + 4 * 16384;

    const int wv   = tid >> 6;                // 0..7 = nt
    const int lane = tid & 63;
    const int col  = lane & 15;
    const int quad = lane >> 4;
    const int r0   = blockIdx.x * 64;         // flattened (n,q); 64 | 256
    const int n    = r0 >> 8;
    const int q0   = r0 & 255;

    // ---- B-frags from global wt into registers (issued first) ----
    frag_u bO[4];
#pragma unroll
    for (int kt = 0; kt < 4; ++kt)
        bO[kt].u = *(const uint4*)(Wt + (size_t)(wv * 16 + col) * 128 + kt * 32 + quad * 8);

    // ---- stage o rows (bf16, channel c = h*32+d) into swizzled LDS ----
#pragma unroll
    for (int i = 0; i < 2; ++i) {
        int idx = i * 512 + tid;       // 0..1023 = 64 rows x 16 slots
        int row = idx >> 4;
        int s   = idx & 15;            // slot -> channels s*8..s*8+7
        int h   = s >> 2;
        int d   = (s & 3) << 3;
        uint4 v = *(const uint4*)(o_ws +
            ((size_t)(n * HH + h) * QDIM + q0 + row) * DD + d);
        *(uint4*)&xl[row * 128 + ((s ^ (row & 7)) << 3)] = v;
    }
    __syncthreads();

    f32x4v acc[4];
#pragma unroll
    for (int mt = 0; mt < 4; ++mt)
        acc[mt] = (f32x4v){0.f, 0.f, 0.f, 0.f};

    const int x7 = col & 7;
#pragma unroll
    for (int mt = 0; mt < 4; ++mt) {
        frag_u a[4];
#pragma unroll
        for (int kt = 0; kt < 4; ++kt)
            a[kt].u = *(const uint4*)&xl[(mt * 16 + col) * 128 +
                                         ((((kt << 2) | quad) ^ x7) << 3)];
#pragma unroll
        for (int kt = 0; kt < 4; ++kt)
            acc[mt] = __builtin_amdgcn_mfma_f32_16x16x32_bf16(a[kt].v, bO[kt].v, acc[mt], 0, 0, 0);
    }

#pragma unroll
    for (int mt = 0; mt < 4; ++mt)
#pragma unroll
        for (int r = 0; r < 4; ++r) {
            size_t row = r0 + mt * 16 + quad * 4 + r;
            out[row * 128 + wv * 16 + col] = acc[mt][r];
        }
}

// =====================================================================
extern "C" void kernel_launch(void* const* d_in, const int* in_sizes, int n_in,
                              void* d_out, int out_size, void* d_ws, size_t ws_size,
                              hipStream_t stream) {
    const float* qx  = (const float*)d_in[0];
    const float* kvx = (const float*)d_in[1];
    const float* tri = (const float*)d_in[2];
    const float* mb  = (const float*)d_in[3];
    // d_in[4] = mask (unused: mask_bias carries it in the reference path)
    const float* Wq  = (const float*)d_in[5];
    const float* Wk  = (const float*)d_in[6];
    const float* Wv  = (const float*)d_in[7];
    const float* Wg  = (const float*)d_in[8];
    const float* Wo  = (const float*)d_in[9];
    float* out = (float*)d_out;

    unsigned short* ws = (unsigned short*)d_ws;
    const size_t RC = (size_t)RROWS * 128;
    unsigned short* q_ws = ws;            // [n][h][q][32]
    unsigned short* k_ws = ws + RC;       // [n][h][k][32]
    unsigned short* v_ws = ws + 2 * RC;   // [n][h][d][key]  (transposed)
    unsigned short* g_ws = ws + 3 * RC;   // [n][h][q][32]
    unsigned short* o_ws = ws + 4 * RC;   // [n][h][q][32]
    unsigned short* wt   = ws + 5 * RC;   // 5 x [128][128] bf16 transposed weights

    prep_weights<<<dim3(40), 256, 0, stream>>>(Wq, Wk, Wv, Wg, Wo, wt);
    proj_mfma<<<dim3(RROWS / 64, 2), 512, 0, stream>>>(
        qx, kvx, wt, q_ws, k_ws, v_ws, g_ws);
    attn_kernel<<<dim3(4096), 256, 0, stream>>>(
        q_ws, k_ws, v_ws, g_ws, tri, mb, o_ws);
    outproj_mfma<<<dim3(RROWS / 64), 512, 0, stream>>>(o_ws, wt, out);
}